// Round 17
// baseline (801.173 us; speedup 1.0000x reference)
//
#include <hip/hip_runtime.h>
#include <hip/hip_bf16.h>
#include <stdint.h>

// ---------------------------------------------------------------------------
// Pipeline (vs r16: gate M=64/wave — single-wave 64-thread blocks, EPB=64,
// 4 sub-tiles per wave so each B-frag feeds 4 MFMAs; halves B-load count,
// the dominant serial term).
//
// ws layout (bytes): as r16 (63.7 MB total).
// ---------------------------------------------------------------------------

typedef __attribute__((ext_vector_type(8))) short short8;
typedef __attribute__((ext_vector_type(4))) float f32x4;
typedef _Float16 half8 __attribute__((ext_vector_type(8)));

#define NN 65536
#define NE1 32768
#define NEG 65536
#define DC 768
#define DR 97
#define DR2 194
#define RELSTR 200
#define RELHS 400
#define KI 194
#define KS 7
#define NT 7
#define EPB 64         // edges per gate block (1 wave x M=64)
#define SSTR 200
#define PSTR 72
#define NDESC_G 4160

#define OFF_REL   0ull
#define OFF_BPK   52428800ull
#define OFF_IDX   62164992ull
#define OFF_SMAX  62427136ull
#define OFF_DEN   62951424ull
#define OFF_META  63475712ull
#define OFF_DESC  63475968ull
#define OFF_WPK   63542528ull

static __device__ __forceinline__ unsigned fkey(float f) {
    unsigned b = __float_as_uint(f);
    return (b & 0x80000000u) ? ~b : (b | 0x80000000u);
}
static __device__ __forceinline__ float funkey(unsigned k) {
    return __uint_as_float((k & 0x80000000u) ? (k & 0x7fffffffu) : ~k);
}
static __device__ __forceinline__ unsigned pk2(_Float16 a, _Float16 b) {
    union { _Float16 h[2]; unsigned u; } x;
    x.h[0] = a; x.h[1] = b;
    return x.u;
}
static __device__ __forceinline__ int nstate(bool zi, bool zx) {
    return zi ? (zx ? 3 : 2) : (zx ? 1 : 0);
}
static __device__ __forceinline__ int nsplit_of(int b) { (void)b; return 4; }
static __device__ __forceinline__ int kindbase_of(int b) { return (b % 3) * 4; }

// ---------------- K1: W_bl1 -> Bpk (b-frag-packed fp16) --------------------
__global__ void build_bpk(const float* __restrict__ W, half8* __restrict__ Bpk) {
    int id = blockIdx.x * blockDim.x + threadIdx.x;
    const int total = KI * KS * NT * 64;
    if (id >= total) return;
    int l = id & 63;
    int g = id >> 6;
    int t = g % NT;
    int ks = (g / NT) % KS;
    int i = g / (NT * KS);
    int kk = t * 16 + (l & 15);
    int jb = ks * 32 + (l >> 4) * 8;
    half8 pk;
#pragma unroll
    for (int m = 0; m < 8; ++m) {
        int j = jb + m;
        float f = (kk < DR && j < DR2) ? W[(size_t)kk * (DR2 * DR2) + i * DR2 + j] : 0.f;
        pk[m] = (_Float16)f;
    }
    Bpk[id] = pk;
}

// ---------------- K1b: W_bl -> Wpk ------------------------------------------
__global__ void build_wpk(const float* __restrict__ Wb, half8* __restrict__ Wpk) {
    int id = blockIdx.x * blockDim.x + threadIdx.x;
    const int total = 24 * NT * 64;
    if (id >= total) return;
    int l = id & 63;
    int g = id >> 6;
    int t = g % NT;
    int k2 = g / NT;
    int col = t * 16 + (l & 15);
    int j0 = k2 * 32 + (l >> 4) * 8;
    half8 pk;
#pragma unroll
    for (int m = 0; m < 8; ++m) {
        float f = (col < DR) ? Wb[(size_t)(j0 + m) * DR + col] : 0.f;
        pk[m] = (_Float16)f;
    }
    Wpk[id] = pk;
}

// ---------------- K2: proj = n @ W_bl via MFMA -------------------------------
__launch_bounds__(512, 8)
__global__ void proj_mfma(const float* __restrict__ nmat, const half8* __restrict__ Wpk,
                          float* __restrict__ proj) {
    __shared__ __align__(16) _Float16 a_lds[128][PSTR];
    int tid = threadIdx.x;
    int r0 = blockIdx.x << 7;
    int w = tid >> 6, lane = tid & 63;
    int er = (w << 4) + (lane & 15);
    int lk = lane >> 4;

    f32x4 acc[NT];
#pragma unroll
    for (int t = 0; t < NT; ++t) acc[t] = (f32x4){0.f, 0.f, 0.f, 0.f};

    int srow = tid >> 2;
    int sc0 = (tid & 3) << 4;
    const float* nrow = nmat + (size_t)(r0 + srow) * DC + sc0;

    for (int k0 = 0; k0 < DC; k0 += 64) {
        __syncthreads();
        {
            const f32x4* p = (const f32x4*)(nrow + k0);
            _Float16* dst = &a_lds[srow][sc0];
#pragma unroll
            for (int q = 0; q < 4; ++q) {
                f32x4 v = p[q];
                *(unsigned*)&dst[q * 4]     = pk2((_Float16)v[0], (_Float16)v[1]);
                *(unsigned*)&dst[q * 4 + 2] = pk2((_Float16)v[2], (_Float16)v[3]);
            }
        }
        __syncthreads();
#pragma unroll
        for (int kk = 0; kk < 2; ++kk) {
            half8 af = *(const half8*)&a_lds[er][kk * 32 + lk * 8];
            const half8* bp = Wpk + (size_t)((k0 >> 5) + kk) * (NT * 64) + lane;
#pragma unroll
            for (int t = 0; t < NT; ++t)
                acc[t] = __builtin_amdgcn_mfma_f32_16x16x32_f16(af, bp[t * 64], acc[t], 0, 0, 0);
        }
    }

#pragma unroll
    for (int t = 0; t < NT; ++t) {
        int col = t * 16 + (lane & 15);
        if (col < DR) {
#pragma unroll
            for (int r = 0; r < 4; ++r) {
                int row = r0 + (w << 4) + lk * 4 + r;
                proj[(size_t)row * DR + col] = acc[t][r];
            }
        }
    }
}

// ---------------- K3: per-edge score + segment max --------------------------
__global__ void score_kernel(const float* __restrict__ proj,
                             const float* __restrict__ e_inter, const float* __restrict__ e_intra,
                             const int* __restrict__ dst_inter, const int* __restrict__ dst_intra,
                             float* __restrict__ s_buf, unsigned* __restrict__ smax_key) {
    int wid = (blockIdx.x * blockDim.x + threadIdx.x) >> 6;
    int lane = threadIdx.x & 63;
    if (wid >= NEG) return;
    int et = wid >> 15, le = wid & (NE1 - 1);
    const float* e = (et ? e_intra : e_inter) + (size_t)le * DR;
    int dst = (et ? dst_intra : dst_inter)[le];
    const float* pr = proj + (size_t)dst * DR;
    float p = pr[lane] * e[lane];
    if (lane < DR - 64) p += pr[lane + 64] * e[lane + 64];
#pragma unroll
    for (int off = 32; off > 0; off >>= 1) p += __shfl_down(p, off);
    if (lane == 0) {
        s_buf[wid] = p;
        atomicMax(&smax_key[et * NN + dst], fkey(p));
    }
}

// ---------------- K4: exp + segment sums ------------------------------------
__global__ void accum_kernel(const float* __restrict__ s_buf,
                             const float* __restrict__ e_inter, const float* __restrict__ e_intra,
                             const int* __restrict__ dst_inter, const int* __restrict__ dst_intra,
                             const unsigned* __restrict__ smax_key,
                             float* __restrict__ denom, float* __restrict__ rel) {
    int wid = (blockIdx.x * blockDim.x + threadIdx.x) >> 6;
    int lane = threadIdx.x & 63;
    if (wid >= NEG) return;
    int et = wid >> 15, le = wid & (NE1 - 1);
    const float* e = (et ? e_intra : e_inter) + (size_t)le * DR;
    int dst = (et ? dst_intra : dst_inter)[le];
    float s = s_buf[wid];
    float mx = funkey(smax_key[et * NN + dst]);
    float ex = __expf(s - mx);
    if (lane == 0) atomicAdd(&denom[et * NN + dst], ex);
    float* rrow = rel + (size_t)dst * RELSTR + et * DR;
    atomicAdd(&rrow[lane], e[lane] * ex);
    if (lane < DR - 64) atomicAdd(&rrow[lane + 64], e[lane + 64] * ex);
}

// ---------------- K5: denom -> 1/denom (0 if empty) -------------------------
__global__ void dinv_kernel(float* __restrict__ denom) {
    int i = blockIdx.x * blockDim.x + threadIdx.x;
    if (i < 2 * NN) {
        float d = denom[i];
        denom[i] = (d > 0.f) ? (1.f / d) : 0.f;
    }
}

// ---------------- K5b: pack rel f32 -> fp16 x dinv, IN PLACE ----------------
__global__ void pack_kernel(float* __restrict__ relf, const float* __restrict__ dinv) {
    int n = blockIdx.x * blockDim.x + threadIdx.x;
    if (n >= NN) return;
    float di0 = dinv[n], di1 = dinv[NN + n];
    unsigned* row = (unsigned*)(relf + (size_t)n * RELSTR);
#pragma unroll 10
    for (int q = 0; q < 50; ++q) {
        uint4 v = *(const uint4*)(row + q * 4);
        int c = q * 4;
        _Float16 h0 = (_Float16)(__uint_as_float(v.x) * ((c + 0 < DR) ? di0 : di1));
        _Float16 h1 = (_Float16)(__uint_as_float(v.y) * ((c + 1 < DR) ? di0 : di1));
        _Float16 h2 = (_Float16)(__uint_as_float(v.z) * ((c + 2 < DR) ? di0 : di1));
        _Float16 h3 = (_Float16)(__uint_as_float(v.w) * ((c + 3 < DR) ? di0 : di1));
        uint2 o;
        o.x = pk2(h0, h1);
        o.y = pk2(h2, h3);
        *(uint2*)(row + q * 2) = o;
    }
}

// ---------------- K6a: classify (LDS histogram) -----------------------------
__global__ void classify_kernel(const float* __restrict__ dinv,
                                const int* __restrict__ src_inter, const int* __restrict__ dst_inter,
                                const int* __restrict__ src_intra, const int* __restrict__ dst_intra,
                                unsigned* __restrict__ meta) {
    __shared__ unsigned h[16];
    if (threadIdx.x < 16) h[threadIdx.x] = 0;
    __syncthreads();
    int gid = blockIdx.x * blockDim.x + threadIdx.x;
    if (gid < NEG) {
        int et = gid >> 15, le = gid & (NE1 - 1);
        int sn = (et ? src_intra : src_inter)[le];
        int dn = (et ? dst_intra : dst_inter)[le];
        int ss = nstate(dinv[sn] == 0.f, dinv[NN + sn] == 0.f);
        int ds = nstate(dinv[dn] == 0.f, dinv[NN + dn] == 0.f);
        int b = (ss == 3 || ds == 3) ? 9 : ss * 3 + ds;
        atomicAdd(&h[b], 1u);
    }
    __syncthreads();
    if (threadIdx.x < 10 && h[threadIdx.x])
        atomicAdd(&meta[threadIdx.x], h[threadIdx.x]);
}

// ---------------- K6b: setup1 -------------------------------------------------
__global__ void setup1_kernel(unsigned* __restrict__ meta) {
    if (threadIdx.x != 0 || blockIdx.x != 0) return;
    unsigned run = 0;
    for (int b = 0; b < 10; ++b) {
        meta[32 + b] = run;
        meta[16 + b] = run;
        run += meta[b];
    }
    unsigned c = 0;
    for (int b = 0; b < 9; ++b) {
        meta[52 + b] = c;
        c += ((meta[b] + EPB - 1) / EPB) * (unsigned)nsplit_of(b);
    }
    meta[48] = c;
}

// ---------------- K6c: setup2 -------------------------------------------------
__global__ void setup2_kernel(const unsigned* __restrict__ meta, uint4* __restrict__ desc) {
    int j = blockIdx.x * blockDim.x + threadIdx.x;
    if (j >= (int)meta[48]) return;
    int b = 8;
    for (int q = 1; q < 9; ++q)
        if (j < (int)meta[52 + q]) { b = q - 1; break; }
    int p = j - (int)meta[52 + b];
    int ns = nsplit_of(b);
    int ci = p / ns;
    int si = p - ci * ns;
    int cnt = (int)meta[b];
    int cbase = (int)meta[32 + b] + ci * EPB;
    int ccnt = cnt - ci * EPB;
    if (ccnt > EPB) ccnt = EPB;
    int kind = kindbase_of(b) + si;
    int sclass = b / 3;
    desc[j] = make_uint4((unsigned)kind, (unsigned)cbase, (unsigned)ccnt, (unsigned)sclass);
}

// ---------------- K6d: scatter ------------------------------------------------
__global__ void scatter_kernel(const float* __restrict__ dinv,
                               const int* __restrict__ src_inter, const int* __restrict__ dst_inter,
                               const int* __restrict__ src_intra, const int* __restrict__ dst_intra,
                               unsigned* __restrict__ meta, int* __restrict__ idxbuf) {
    __shared__ unsigned cur[16];
    __shared__ unsigned base[16];
    if (threadIdx.x < 16) cur[threadIdx.x] = 0;
    __syncthreads();
    int gid = blockIdx.x * blockDim.x + threadIdx.x;
    int b = -1;
    unsigned r = 0;
    if (gid < NEG) {
        int et = gid >> 15, le = gid & (NE1 - 1);
        int sn = (et ? src_intra : src_inter)[le];
        int dn = (et ? dst_intra : dst_inter)[le];
        int ss = nstate(dinv[sn] == 0.f, dinv[NN + sn] == 0.f);
        int ds = nstate(dinv[dn] == 0.f, dinv[NN + dn] == 0.f);
        b = (ss == 3 || ds == 3) ? 9 : ss * 3 + ds;
        r = atomicAdd(&cur[b], 1u);
    }
    __syncthreads();
    if (threadIdx.x < 10 && cur[threadIdx.x])
        base[threadIdx.x] = atomicAdd(&meta[16 + threadIdx.x], cur[threadIdx.x]);
    __syncthreads();
    if (b >= 0) idxbuf[base[b] + r] = gid;
}

// ---------------- K7: skip-class edges --------------------------------------
__global__ void skip_kernel(const unsigned* __restrict__ meta, const int* __restrict__ idxbuf,
                            const float* __restrict__ e_inter, const float* __restrict__ e_intra,
                            const float* __restrict__ bias, float* __restrict__ out) {
    int n9 = (int)meta[9];
    int base9 = (int)meta[41];
    int k = threadIdx.x;
    float g = 0.f;
    if (k < DR) {
        float b = bias[k];
        g = 1.f + 1.f / (1.f + __expf(-b));
    }
    for (int q = blockIdx.x; q < n9; q += gridDim.x) {
        int gid = idxbuf[base9 + q];
        int et = gid >> 15, le = gid & (NE1 - 1);
        const float* e = (et ? e_intra : e_inter) + (size_t)le * DR;
        if (k < DR) out[(size_t)gid * DR + k] = e[k] * g;
    }
}

// ---------------- K8 epilogue sub-macro (one sub-tile) ----------------------
#define EPI_SUB(ACC, AOFF)                                                     \
    _Pragma("unroll")                                                          \
    for (int r = 0; r < 4; ++r) {                                              \
        int row = (AOFF) + lk * 4 + r;                                         \
        if (row < ccnt) {                                                      \
            int gid = idxbuf[cbase + row];                                     \
            int et = gid >> 15, le = gid & (NE1 - 1);                          \
            const float* e = (et ? e_intra : e_inter) + (size_t)le * DR;       \
            float* o = out + (size_t)gid * DR;                                 \
            _Pragma("unroll")                                                  \
            for (int tt = 0; tt < NTTv; ++tt) {                                \
                int k = (T0c + tt) * 16 + (lane & 15);                         \
                if (k < DR) {                                                  \
                    float g = ACC[tt][r] + bias[k];                            \
                    float sg = 1.f / (1.f + __expf(-g));                       \
                    o[k] = e[k] * (1.f + sg);                                  \
                }                                                              \
            }                                                                  \
        }                                                                      \
    }

// ---------------- K8 compute body as MACRO: M=64/wave (4 sub-tiles / B) -----
#define GATE_BODY(KS0v, KS1v, T0v, T1v)                                        \
    {                                                                          \
        constexpr int NKSv = (KS1v) - (KS0v);                                  \
        constexpr int NTTv = (T1v) - (T0v);                                    \
        constexpr int T0c = (T0v);                                             \
        f32x4 acc0[NTTv], acc1[NTTv], acc2[NTTv], acc3[NTTv];                  \
        _Pragma("unroll")                                                      \
        for (int tt = 0; tt < NTTv; ++tt) {                                    \
            acc0[tt] = (f32x4){0.f, 0.f, 0.f, 0.f};                            \
            acc1[tt] = (f32x4){0.f, 0.f, 0.f, 0.f};                            \
            acc2[tt] = (f32x4){0.f, 0.f, 0.f, 0.f};                            \
            acc3[tt] = (f32x4){0.f, 0.f, 0.f, 0.f};                            \
        }                                                                      \
        const half8* bl = Bpk + lane;                                          \
        for (int i = i0; i < iEnd; ++i) {                                      \
            _Float16 s0 = buf[er0 * SSTR + i];                                 \
            _Float16 s1 = buf[er1 * SSTR + i];                                 \
            _Float16 s2 = buf[er2 * SSTR + i];                                 \
            _Float16 s3 = buf[er3 * SSTR + i];                                 \
            half8 sv0 = {s0, s0, s0, s0, s0, s0, s0, s0};                      \
            half8 sv1 = {s1, s1, s1, s1, s1, s1, s1, s1};                      \
            half8 sv2 = {s2, s2, s2, s2, s2, s2, s2, s2};                      \
            half8 sv3 = {s3, s3, s3, s3, s3, s3, s3, s3};                      \
            const half8* bi = bl + (size_t)((i * KS + (KS0v)) * NT + (T0v)) * 64; \
            _Pragma("unroll")                                                  \
            for (int ks = 0; ks < NKSv; ++ks) {                                \
                half8 af0 = sv0 * dv0[(KS0v) + ks];                            \
                half8 af1 = sv1 * dv1[(KS0v) + ks];                            \
                half8 af2 = sv2 * dv2[(KS0v) + ks];                            \
                half8 af3 = sv3 * dv3[(KS0v) + ks];                            \
                _Pragma("unroll")                                              \
                for (int tt = 0; tt < NTTv; ++tt) {                            \
                    half8 bv = bi[(ks * NT + tt) * 64];                        \
                    acc0[tt] = __builtin_amdgcn_mfma_f32_16x16x32_f16(af0, bv, acc0[tt], 0, 0, 0); \
                    acc1[tt] = __builtin_amdgcn_mfma_f32_16x16x32_f16(af1, bv, acc1[tt], 0, 0, 0); \
                    acc2[tt] = __builtin_amdgcn_mfma_f32_16x16x32_f16(af2, bv, acc2[tt], 0, 0, 0); \
                    acc3[tt] = __builtin_amdgcn_mfma_f32_16x16x32_f16(af3, bv, acc3[tt], 0, 0, 0); \
                }                                                              \
            }                                                                  \
        }                                                                      \
        EPI_SUB(acc0, 0)                                                       \
        EPI_SUB(acc1, 16)                                                      \
        EPI_SUB(acc2, 32)                                                      \
        EPI_SUB(acc3, 48)                                                      \
    }

// ---------------- K8: unified bilinear gate (1 wave, M=64) ------------------
__launch_bounds__(64, 2)
__global__ void gate_all(const _Float16* __restrict__ relh, const float* __restrict__ dinv,
                         const half8* __restrict__ Bpk, const float* __restrict__ bias,
                         const int* __restrict__ src_inter, const int* __restrict__ dst_inter,
                         const int* __restrict__ src_intra, const int* __restrict__ dst_intra,
                         const float* __restrict__ e_inter, const float* __restrict__ e_intra,
                         const int* __restrict__ idxbuf, const unsigned* __restrict__ meta,
                         const uint4* __restrict__ desc, float* __restrict__ out) {
    if (blockIdx.x >= meta[48]) return;
    uint4 de = desc[blockIdx.x];
    int kind = (int)de.x;
    int cbase = (int)de.y;
    int ccnt = (int)de.z;
    int sclass = (int)de.w;
    int i0 = (sclass == 2) ? DR : 0;
    int iEnd = (sclass == 0) ? DR2 : (i0 + DR);

    __shared__ __align__(16) _Float16 buf[EPB * SSTR];   // 25,600 B time-shared
    int tid = threadIdx.x;                                // 64 (one wave)
    int lane = tid;
    int lk = lane >> 4;
    int er0 = lane & 15;
    int er1 = er0 + 16;
    int er2 = er0 + 32;
    int er3 = er0 + 48;

    // ---- phase 1: copy d rows (pre-scaled fp16) -> LDS (one row/thread) ----
    {
        int edge = tid;
        int rc = cbase + ((edge < ccnt) ? edge : (ccnt - 1));
        int gid = idxbuf[rc];
        int et = gid >> 15, le = gid & (NE1 - 1);
        int dn = (et ? dst_intra : dst_inter)[le];
        const uint4* rp = (const uint4*)(relh + (size_t)dn * RELHS);
        uint4* dp = (uint4*)&buf[edge * SSTR];
#pragma unroll
        for (int q = 0; q < 25; ++q) dp[q] = rp[q];
    }
    __syncthreads();

    // ---- consume d rows into registers (LDS->reg, 4 sub-tiles) ----
    half8 dv0[KS], dv1[KS], dv2[KS], dv3[KS];
#pragma unroll
    for (int ks = 0; ks < KS; ++ks) {
        if (ks == 6 && lk > 0) {          // cols >= 200 are K-padding: zero
            dv0[ks] = (half8){0, 0, 0, 0, 0, 0, 0, 0};
            dv1[ks] = (half8){0, 0, 0, 0, 0, 0, 0, 0};
            dv2[ks] = (half8){0, 0, 0, 0, 0, 0, 0, 0};
            dv3[ks] = (half8){0, 0, 0, 0, 0, 0, 0, 0};
        } else {
            dv0[ks] = *(const half8*)&buf[er0 * SSTR + ks * 32 + lk * 8];
            dv1[ks] = *(const half8*)&buf[er1 * SSTR + ks * 32 + lk * 8];
            dv2[ks] = *(const half8*)&buf[er2 * SSTR + ks * 32 + lk * 8];
            dv3[ks] = *(const half8*)&buf[er3 * SSTR + ks * 32 + lk * 8];
        }
    }
    __syncthreads();

    // ---- phase 2: copy s rows into the SAME buffer ----
    {
        int edge = tid;
        int rc = cbase + ((edge < ccnt) ? edge : (ccnt - 1));
        int gid = idxbuf[rc];
        int et = gid >> 15, le = gid & (NE1 - 1);
        int sn = (et ? src_intra : src_inter)[le];
        const uint4* rp = (const uint4*)(relh + (size_t)sn * RELHS);
        uint4* dp = (uint4*)&buf[edge * SSTR];
#pragma unroll
        for (int q = 0; q < 25; ++q) dp[q] = rp[q];
    }
    __syncthreads();

    switch (kind) {
        case 0:  GATE_BODY(0, 7, 0, 2); break;
        case 1:  GATE_BODY(0, 7, 2, 4); break;
        case 2:  GATE_BODY(0, 7, 4, 6); break;
        case 3:  GATE_BODY(0, 7, 6, 7); break;
        case 4:  GATE_BODY(0, 4, 0, 2); break;
        case 5:  GATE_BODY(0, 4, 2, 4); break;
        case 6:  GATE_BODY(0, 4, 4, 6); break;
        case 7:  GATE_BODY(0, 4, 6, 7); break;
        case 8:  GATE_BODY(3, 7, 0, 2); break;
        case 9:  GATE_BODY(3, 7, 2, 4); break;
        case 10: GATE_BODY(3, 7, 4, 6); break;
        case 11: GATE_BODY(3, 7, 6, 7); break;
        default: break;
    }
}

// ---------------------------------------------------------------------------
extern "C" void kernel_launch(void* const* d_in, const int* in_sizes, int n_in,
                              void* d_out, int out_size, void* d_ws, size_t ws_size,
                              hipStream_t stream) {
    (void)in_sizes; (void)n_in; (void)out_size; (void)ws_size;
    const float* nmat     = (const float*)d_in[0];
    const float* e_inter  = (const float*)d_in[1];
    const float* e_intra  = (const float*)d_in[2];
    const float* W_bl     = (const float*)d_in[3];
    const float* W_bl1    = (const float*)d_in[4];
    const float* b_bl1    = (const float*)d_in[5];
    const int* src_inter  = (const int*)d_in[6];
    const int* dst_inter  = (const int*)d_in[7];
    const int* src_intra  = (const int*)d_in[8];
    const int* dst_intra  = (const int*)d_in[9];
    float* out = (float*)d_out;

    char* ws = (char*)d_ws;
    float* regA     = (float*)(ws + OFF_REL);
    half8* Bpk      = (half8*)(ws + OFF_BPK);
    int* idxbuf     = (int*)(ws + OFF_IDX);
    float* s_buf    = (float*)(ws + OFF_IDX);
    unsigned* smax  = (unsigned*)(ws + OFF_SMAX);
    float* denom    = (float*)(ws + OFF_DEN);
    unsigned* meta  = (unsigned*)(ws + OFF_META);
    uint4* desc     = (uint4*)(ws + OFF_DESC);
    half8* Wpk      = (half8*)(ws + OFF_WPK);

    hipMemsetAsync(smax, 0, 524288, stream);
    hipMemsetAsync(denom, 0, 524288, stream);
    hipMemsetAsync(meta, 0, 256, stream);

    build_bpk<<<(KI * KS * NT * 64 + 255) / 256, 256, 0, stream>>>(W_bl1, Bpk);
    build_wpk<<<(24 * NT * 64 + 255) / 256, 256, 0, stream>>>(W_bl, Wpk);
    proj_mfma<<<NN / 128, 512, 0, stream>>>(nmat, Wpk, regA);
    score_kernel<<<NEG / 4, 256, 0, stream>>>(regA, e_inter, e_intra, dst_inter, dst_intra,
                                              s_buf, smax);
    hipMemsetAsync(regA, 0, 52428800, stream);   // proj dead; regA becomes rel
    accum_kernel<<<NEG / 4, 256, 0, stream>>>(s_buf, e_inter, e_intra, dst_inter, dst_intra,
                                              smax, denom, regA);
    dinv_kernel<<<512, 256, 0, stream>>>(denom);
    pack_kernel<<<NN / 256, 256, 0, stream>>>(regA, denom);
    classify_kernel<<<NEG / 256, 256, 0, stream>>>(denom, src_inter, dst_inter,
                                                   src_intra, dst_intra, meta);
    setup1_kernel<<<1, 64, 0, stream>>>(meta);
    setup2_kernel<<<(NDESC_G + 255) / 256, 256, 0, stream>>>(meta, desc);
    scatter_kernel<<<NEG / 256, 256, 0, stream>>>(denom, src_inter, dst_inter,
                                                  src_intra, dst_intra, meta, idxbuf);
    skip_kernel<<<2048, 128, 0, stream>>>(meta, idxbuf, e_inter, e_intra, b_bl1, out);
    gate_all<<<NDESC_G, 64, 0, stream>>>((const _Float16*)regA, denom, Bpk, b_bl1,
                                         src_inter, dst_inter, src_intra, dst_intra,
                                         e_inter, e_intra, idxbuf, meta, desc, out);
}

// Round 18
// 566.222 us; speedup vs baseline: 1.4149x; 1.4149x over previous
//
#include <hip/hip_runtime.h>
#include <hip/hip_bf16.h>
#include <stdint.h>

// ---------------------------------------------------------------------------
// Pipeline (r16 proven config; staging now uses all 128 threads, 2/row):
//  K8 gate_all : EPB=64, 2 waves/blk, M=32/wave, NTT=2 pieces, time-shared
//                25.6 KB LDS, raw fp16 row-copy staging, compile-time ks/t.
//
// ws layout (bytes): as r16 (63.7 MB total).
// ---------------------------------------------------------------------------

typedef __attribute__((ext_vector_type(8))) short short8;
typedef __attribute__((ext_vector_type(4))) float f32x4;
typedef _Float16 half8 __attribute__((ext_vector_type(8)));

#define NN 65536
#define NE1 32768
#define NEG 65536
#define DC 768
#define DR 97
#define DR2 194
#define RELSTR 200
#define RELHS 400
#define KI 194
#define KS 7
#define NT 7
#define EPB 64         // edges per gate block (2 waves x M=32)
#define SSTR 200
#define PSTR 72
#define NDESC_G 4160

#define OFF_REL   0ull
#define OFF_BPK   52428800ull
#define OFF_IDX   62164992ull
#define OFF_SMAX  62427136ull
#define OFF_DEN   62951424ull
#define OFF_META  63475712ull
#define OFF_DESC  63475968ull
#define OFF_WPK   63542528ull

static __device__ __forceinline__ unsigned fkey(float f) {
    unsigned b = __float_as_uint(f);
    return (b & 0x80000000u) ? ~b : (b | 0x80000000u);
}
static __device__ __forceinline__ float funkey(unsigned k) {
    return __uint_as_float((k & 0x80000000u) ? (k & 0x7fffffffu) : ~k);
}
static __device__ __forceinline__ unsigned pk2(_Float16 a, _Float16 b) {
    union { _Float16 h[2]; unsigned u; } x;
    x.h[0] = a; x.h[1] = b;
    return x.u;
}
static __device__ __forceinline__ int nstate(bool zi, bool zx) {
    return zi ? (zx ? 3 : 2) : (zx ? 1 : 0);
}
static __device__ __forceinline__ int nsplit_of(int b) { (void)b; return 4; }
static __device__ __forceinline__ int kindbase_of(int b) { return (b % 3) * 4; }

// ---------------- K1: W_bl1 -> Bpk (b-frag-packed fp16) --------------------
__global__ void build_bpk(const float* __restrict__ W, half8* __restrict__ Bpk) {
    int id = blockIdx.x * blockDim.x + threadIdx.x;
    const int total = KI * KS * NT * 64;
    if (id >= total) return;
    int l = id & 63;
    int g = id >> 6;
    int t = g % NT;
    int ks = (g / NT) % KS;
    int i = g / (NT * KS);
    int kk = t * 16 + (l & 15);
    int jb = ks * 32 + (l >> 4) * 8;
    half8 pk;
#pragma unroll
    for (int m = 0; m < 8; ++m) {
        int j = jb + m;
        float f = (kk < DR && j < DR2) ? W[(size_t)kk * (DR2 * DR2) + i * DR2 + j] : 0.f;
        pk[m] = (_Float16)f;
    }
    Bpk[id] = pk;
}

// ---------------- K1b: W_bl -> Wpk ------------------------------------------
__global__ void build_wpk(const float* __restrict__ Wb, half8* __restrict__ Wpk) {
    int id = blockIdx.x * blockDim.x + threadIdx.x;
    const int total = 24 * NT * 64;
    if (id >= total) return;
    int l = id & 63;
    int g = id >> 6;
    int t = g % NT;
    int k2 = g / NT;
    int col = t * 16 + (l & 15);
    int j0 = k2 * 32 + (l >> 4) * 8;
    half8 pk;
#pragma unroll
    for (int m = 0; m < 8; ++m) {
        float f = (col < DR) ? Wb[(size_t)(j0 + m) * DR + col] : 0.f;
        pk[m] = (_Float16)f;
    }
    Wpk[id] = pk;
}

// ---------------- K2: proj = n @ W_bl via MFMA -------------------------------
__launch_bounds__(512, 8)
__global__ void proj_mfma(const float* __restrict__ nmat, const half8* __restrict__ Wpk,
                          float* __restrict__ proj) {
    __shared__ __align__(16) _Float16 a_lds[128][PSTR];
    int tid = threadIdx.x;
    int r0 = blockIdx.x << 7;
    int w = tid >> 6, lane = tid & 63;
    int er = (w << 4) + (lane & 15);
    int lk = lane >> 4;

    f32x4 acc[NT];
#pragma unroll
    for (int t = 0; t < NT; ++t) acc[t] = (f32x4){0.f, 0.f, 0.f, 0.f};

    int srow = tid >> 2;
    int sc0 = (tid & 3) << 4;
    const float* nrow = nmat + (size_t)(r0 + srow) * DC + sc0;

    for (int k0 = 0; k0 < DC; k0 += 64) {
        __syncthreads();
        {
            const f32x4* p = (const f32x4*)(nrow + k0);
            _Float16* dst = &a_lds[srow][sc0];
#pragma unroll
            for (int q = 0; q < 4; ++q) {
                f32x4 v = p[q];
                *(unsigned*)&dst[q * 4]     = pk2((_Float16)v[0], (_Float16)v[1]);
                *(unsigned*)&dst[q * 4 + 2] = pk2((_Float16)v[2], (_Float16)v[3]);
            }
        }
        __syncthreads();
#pragma unroll
        for (int kk = 0; kk < 2; ++kk) {
            half8 af = *(const half8*)&a_lds[er][kk * 32 + lk * 8];
            const half8* bp = Wpk + (size_t)((k0 >> 5) + kk) * (NT * 64) + lane;
#pragma unroll
            for (int t = 0; t < NT; ++t)
                acc[t] = __builtin_amdgcn_mfma_f32_16x16x32_f16(af, bp[t * 64], acc[t], 0, 0, 0);
        }
    }

#pragma unroll
    for (int t = 0; t < NT; ++t) {
        int col = t * 16 + (lane & 15);
        if (col < DR) {
#pragma unroll
            for (int r = 0; r < 4; ++r) {
                int row = r0 + (w << 4) + lk * 4 + r;
                proj[(size_t)row * DR + col] = acc[t][r];
            }
        }
    }
}

// ---------------- K3: per-edge score + segment max --------------------------
__global__ void score_kernel(const float* __restrict__ proj,
                             const float* __restrict__ e_inter, const float* __restrict__ e_intra,
                             const int* __restrict__ dst_inter, const int* __restrict__ dst_intra,
                             float* __restrict__ s_buf, unsigned* __restrict__ smax_key) {
    int wid = (blockIdx.x * blockDim.x + threadIdx.x) >> 6;
    int lane = threadIdx.x & 63;
    if (wid >= NEG) return;
    int et = wid >> 15, le = wid & (NE1 - 1);
    const float* e = (et ? e_intra : e_inter) + (size_t)le * DR;
    int dst = (et ? dst_intra : dst_inter)[le];
    const float* pr = proj + (size_t)dst * DR;
    float p = pr[lane] * e[lane];
    if (lane < DR - 64) p += pr[lane + 64] * e[lane + 64];
#pragma unroll
    for (int off = 32; off > 0; off >>= 1) p += __shfl_down(p, off);
    if (lane == 0) {
        s_buf[wid] = p;
        atomicMax(&smax_key[et * NN + dst], fkey(p));
    }
}

// ---------------- K4: exp + segment sums ------------------------------------
__global__ void accum_kernel(const float* __restrict__ s_buf,
                             const float* __restrict__ e_inter, const float* __restrict__ e_intra,
                             const int* __restrict__ dst_inter, const int* __restrict__ dst_intra,
                             const unsigned* __restrict__ smax_key,
                             float* __restrict__ denom, float* __restrict__ rel) {
    int wid = (blockIdx.x * blockDim.x + threadIdx.x) >> 6;
    int lane = threadIdx.x & 63;
    if (wid >= NEG) return;
    int et = wid >> 15, le = wid & (NE1 - 1);
    const float* e = (et ? e_intra : e_inter) + (size_t)le * DR;
    int dst = (et ? dst_intra : dst_inter)[le];
    float s = s_buf[wid];
    float mx = funkey(smax_key[et * NN + dst]);
    float ex = __expf(s - mx);
    if (lane == 0) atomicAdd(&denom[et * NN + dst], ex);
    float* rrow = rel + (size_t)dst * RELSTR + et * DR;
    atomicAdd(&rrow[lane], e[lane] * ex);
    if (lane < DR - 64) atomicAdd(&rrow[lane + 64], e[lane + 64] * ex);
}

// ---------------- K5: denom -> 1/denom (0 if empty) -------------------------
__global__ void dinv_kernel(float* __restrict__ denom) {
    int i = blockIdx.x * blockDim.x + threadIdx.x;
    if (i < 2 * NN) {
        float d = denom[i];
        denom[i] = (d > 0.f) ? (1.f / d) : 0.f;
    }
}

// ---------------- K5b: pack rel f32 -> fp16 x dinv, IN PLACE ----------------
__global__ void pack_kernel(float* __restrict__ relf, const float* __restrict__ dinv) {
    int n = blockIdx.x * blockDim.x + threadIdx.x;
    if (n >= NN) return;
    float di0 = dinv[n], di1 = dinv[NN + n];
    unsigned* row = (unsigned*)(relf + (size_t)n * RELSTR);
#pragma unroll 10
    for (int q = 0; q < 50; ++q) {
        uint4 v = *(const uint4*)(row + q * 4);
        int c = q * 4;
        _Float16 h0 = (_Float16)(__uint_as_float(v.x) * ((c + 0 < DR) ? di0 : di1));
        _Float16 h1 = (_Float16)(__uint_as_float(v.y) * ((c + 1 < DR) ? di0 : di1));
        _Float16 h2 = (_Float16)(__uint_as_float(v.z) * ((c + 2 < DR) ? di0 : di1));
        _Float16 h3 = (_Float16)(__uint_as_float(v.w) * ((c + 3 < DR) ? di0 : di1));
        uint2 o;
        o.x = pk2(h0, h1);
        o.y = pk2(h2, h3);
        *(uint2*)(row + q * 2) = o;
    }
}

// ---------------- K6a: classify (LDS histogram) -----------------------------
__global__ void classify_kernel(const float* __restrict__ dinv,
                                const int* __restrict__ src_inter, const int* __restrict__ dst_inter,
                                const int* __restrict__ src_intra, const int* __restrict__ dst_intra,
                                unsigned* __restrict__ meta) {
    __shared__ unsigned h[16];
    if (threadIdx.x < 16) h[threadIdx.x] = 0;
    __syncthreads();
    int gid = blockIdx.x * blockDim.x + threadIdx.x;
    if (gid < NEG) {
        int et = gid >> 15, le = gid & (NE1 - 1);
        int sn = (et ? src_intra : src_inter)[le];
        int dn = (et ? dst_intra : dst_inter)[le];
        int ss = nstate(dinv[sn] == 0.f, dinv[NN + sn] == 0.f);
        int ds = nstate(dinv[dn] == 0.f, dinv[NN + dn] == 0.f);
        int b = (ss == 3 || ds == 3) ? 9 : ss * 3 + ds;
        atomicAdd(&h[b], 1u);
    }
    __syncthreads();
    if (threadIdx.x < 10 && h[threadIdx.x])
        atomicAdd(&meta[threadIdx.x], h[threadIdx.x]);
}

// ---------------- K6b: setup1 -------------------------------------------------
__global__ void setup1_kernel(unsigned* __restrict__ meta) {
    if (threadIdx.x != 0 || blockIdx.x != 0) return;
    unsigned run = 0;
    for (int b = 0; b < 10; ++b) {
        meta[32 + b] = run;
        meta[16 + b] = run;
        run += meta[b];
    }
    unsigned c = 0;
    for (int b = 0; b < 9; ++b) {
        meta[52 + b] = c;
        c += ((meta[b] + EPB - 1) / EPB) * (unsigned)nsplit_of(b);
    }
    meta[48] = c;
}

// ---------------- K6c: setup2 -------------------------------------------------
__global__ void setup2_kernel(const unsigned* __restrict__ meta, uint4* __restrict__ desc) {
    int j = blockIdx.x * blockDim.x + threadIdx.x;
    if (j >= (int)meta[48]) return;
    int b = 8;
    for (int q = 1; q < 9; ++q)
        if (j < (int)meta[52 + q]) { b = q - 1; break; }
    int p = j - (int)meta[52 + b];
    int ns = nsplit_of(b);
    int ci = p / ns;
    int si = p - ci * ns;
    int cnt = (int)meta[b];
    int cbase = (int)meta[32 + b] + ci * EPB;
    int ccnt = cnt - ci * EPB;
    if (ccnt > EPB) ccnt = EPB;
    int kind = kindbase_of(b) + si;
    int sclass = b / 3;
    desc[j] = make_uint4((unsigned)kind, (unsigned)cbase, (unsigned)ccnt, (unsigned)sclass);
}

// ---------------- K6d: scatter ------------------------------------------------
__global__ void scatter_kernel(const float* __restrict__ dinv,
                               const int* __restrict__ src_inter, const int* __restrict__ dst_inter,
                               const int* __restrict__ src_intra, const int* __restrict__ dst_intra,
                               unsigned* __restrict__ meta, int* __restrict__ idxbuf) {
    __shared__ unsigned cur[16];
    __shared__ unsigned base[16];
    if (threadIdx.x < 16) cur[threadIdx.x] = 0;
    __syncthreads();
    int gid = blockIdx.x * blockDim.x + threadIdx.x;
    int b = -1;
    unsigned r = 0;
    if (gid < NEG) {
        int et = gid >> 15, le = gid & (NE1 - 1);
        int sn = (et ? src_intra : src_inter)[le];
        int dn = (et ? dst_intra : dst_inter)[le];
        int ss = nstate(dinv[sn] == 0.f, dinv[NN + sn] == 0.f);
        int ds = nstate(dinv[dn] == 0.f, dinv[NN + dn] == 0.f);
        b = (ss == 3 || ds == 3) ? 9 : ss * 3 + ds;
        r = atomicAdd(&cur[b], 1u);
    }
    __syncthreads();
    if (threadIdx.x < 10 && cur[threadIdx.x])
        base[threadIdx.x] = atomicAdd(&meta[16 + threadIdx.x], cur[threadIdx.x]);
    __syncthreads();
    if (b >= 0) idxbuf[base[b] + r] = gid;
}

// ---------------- K7: skip-class edges --------------------------------------
__global__ void skip_kernel(const unsigned* __restrict__ meta, const int* __restrict__ idxbuf,
                            const float* __restrict__ e_inter, const float* __restrict__ e_intra,
                            const float* __restrict__ bias, float* __restrict__ out) {
    int n9 = (int)meta[9];
    int base9 = (int)meta[41];
    int k = threadIdx.x;
    float g = 0.f;
    if (k < DR) {
        float b = bias[k];
        g = 1.f + 1.f / (1.f + __expf(-b));
    }
    for (int q = blockIdx.x; q < n9; q += gridDim.x) {
        int gid = idxbuf[base9 + q];
        int et = gid >> 15, le = gid & (NE1 - 1);
        const float* e = (et ? e_intra : e_inter) + (size_t)le * DR;
        if (k < DR) out[(size_t)gid * DR + k] = e[k] * g;
    }
}

// ---------------- K8 compute body as MACRO (M=32/wave) ----------------------
#define GATE_BODY(KS0v, KS1v, T0v, T1v)                                        \
    {                                                                          \
        constexpr int NKSv = (KS1v) - (KS0v);                                  \
        constexpr int NTTv = (T1v) - (T0v);                                    \
        f32x4 acc0[NTTv], acc1[NTTv];                                          \
        _Pragma("unroll")                                                      \
        for (int tt = 0; tt < NTTv; ++tt) {                                    \
            acc0[tt] = (f32x4){0.f, 0.f, 0.f, 0.f};                            \
            acc1[tt] = (f32x4){0.f, 0.f, 0.f, 0.f};                            \
        }                                                                      \
        const half8* bl = Bpk + lane;                                          \
        for (int i = i0; i < iEnd; ++i) {                                      \
            _Float16 s0 = buf[er0 * SSTR + i];                                 \
            _Float16 s1 = buf[er1 * SSTR + i];                                 \
            half8 sv0 = {s0, s0, s0, s0, s0, s0, s0, s0};                      \
            half8 sv1 = {s1, s1, s1, s1, s1, s1, s1, s1};                      \
            const half8* bi = bl + (size_t)((i * KS + (KS0v)) * NT + (T0v)) * 64; \
            _Pragma("unroll")                                                  \
            for (int ks = 0; ks < NKSv; ++ks) {                                \
                half8 af0 = sv0 * dv0[(KS0v) + ks];                            \
                half8 af1 = sv1 * dv1[(KS0v) + ks];                            \
                _Pragma("unroll")                                              \
                for (int tt = 0; tt < NTTv; ++tt) {                            \
                    half8 bv = bi[(ks * NT + tt) * 64];                        \
                    acc0[tt] = __builtin_amdgcn_mfma_f32_16x16x32_f16(af0, bv, acc0[tt], 0, 0, 0); \
                    acc1[tt] = __builtin_amdgcn_mfma_f32_16x16x32_f16(af1, bv, acc1[tt], 0, 0, 0); \
                }                                                              \
            }                                                                  \
        }                                                                      \
        _Pragma("unroll")                                                      \
        for (int r = 0; r < 4; ++r) {                                          \
            int row = (w << 5) + lk * 4 + r;                                   \
            if (row < ccnt) {                                                  \
                int gid = idxbuf[cbase + row];                                 \
                int et = gid >> 15, le = gid & (NE1 - 1);                      \
                const float* e = (et ? e_intra : e_inter) + (size_t)le * DR;   \
                float* o = out + (size_t)gid * DR;                             \
                _Pragma("unroll")                                              \
                for (int tt = 0; tt < NTTv; ++tt) {                            \
                    int k = ((T0v) + tt) * 16 + (lane & 15);                   \
                    if (k < DR) {                                              \
                        float g = acc0[tt][r] + bias[k];                       \
                        float sg = 1.f / (1.f + __expf(-g));                   \
                        o[k] = e[k] * (1.f + sg);                              \
                    }                                                          \
                }                                                              \
            }                                                                  \
        }                                                                      \
        _Pragma("unroll")                                                      \
        for (int r = 0; r < 4; ++r) {                                          \
            int row = (w << 5) + 16 + lk * 4 + r;                              \
            if (row < ccnt) {                                                  \
                int gid = idxbuf[cbase + row];                                 \
                int et = gid >> 15, le = gid & (NE1 - 1);                      \
                const float* e = (et ? e_intra : e_inter) + (size_t)le * DR;   \
                float* o = out + (size_t)gid * DR;                             \
                _Pragma("unroll")                                              \
                for (int tt = 0; tt < NTTv; ++tt) {                            \
                    int k = ((T0v) + tt) * 16 + (lane & 15);                   \
                    if (k < DR) {                                              \
                        float g = acc1[tt][r] + bias[k];                       \
                        float sg = 1.f / (1.f + __expf(-g));                   \
                        o[k] = e[k] * (1.f + sg);                              \
                    }                                                          \
                }                                                              \
            }                                                                  \
        }                                                                      \
    }

// ---------------- K8: unified bilinear gate (EPB=64, 2 waves, M=32) ---------
__launch_bounds__(128, 4)
__global__ void gate_all(const _Float16* __restrict__ relh, const float* __restrict__ dinv,
                         const half8* __restrict__ Bpk, const float* __restrict__ bias,
                         const int* __restrict__ src_inter, const int* __restrict__ dst_inter,
                         const int* __restrict__ src_intra, const int* __restrict__ dst_intra,
                         const float* __restrict__ e_inter, const float* __restrict__ e_intra,
                         const int* __restrict__ idxbuf, const unsigned* __restrict__ meta,
                         const uint4* __restrict__ desc, float* __restrict__ out) {
    if (blockIdx.x >= meta[48]) return;
    uint4 de = desc[blockIdx.x];
    int kind = (int)de.x;
    int cbase = (int)de.y;
    int ccnt = (int)de.z;
    int sclass = (int)de.w;
    int i0 = (sclass == 2) ? DR : 0;
    int iEnd = (sclass == 0) ? DR2 : (i0 + DR);

    __shared__ __align__(16) _Float16 buf[EPB * SSTR];   // 25,600 B time-shared
    int tid = threadIdx.x;                                // 128
    int w = tid >> 6;                                     // wave 0..1
    int lane = tid & 63;
    int lk = lane >> 4;
    int er0 = (w << 5) + (lane & 15);
    int er1 = er0 + 16;

    // ---- phase 1: copy d rows (pre-scaled fp16) -> LDS (2 threads/row) ----
    {
        int edge = tid >> 1;
        int h = tid & 1;                  // h=0: q 0..12, h=1: q 13..24
        int rc = cbase + ((edge < ccnt) ? edge : (ccnt - 1));
        int gid = idxbuf[rc];
        int et = gid >> 15, le = gid & (NE1 - 1);
        int dn = (et ? dst_intra : dst_inter)[le];
        const uint4* rp = (const uint4*)(relh + (size_t)dn * RELHS);
        uint4* dp = (uint4*)&buf[edge * SSTR];
        int q0 = h * 13;
        int q1 = q0 + 13 - h;             // 13 or 12 chunks
        for (int q = q0; q < q1; ++q) dp[q] = rp[q];
    }
    __syncthreads();

    half8 dv0[KS], dv1[KS];
#pragma unroll
    for (int ks = 0; ks < KS; ++ks) {
        if (ks == 6 && lk > 0) {
            dv0[ks] = (half8){0, 0, 0, 0, 0, 0, 0, 0};
            dv1[ks] = (half8){0, 0, 0, 0, 0, 0, 0, 0};
        } else {
            dv0[ks] = *(const half8*)&buf[er0 * SSTR + ks * 32 + lk * 8];
            dv1[ks] = *(const half8*)&buf[er1 * SSTR + ks * 32 + lk * 8];
        }
    }
    __syncthreads();

    // ---- phase 2: copy s rows into the SAME buffer (2 threads/row) ----
    {
        int edge = tid >> 1;
        int h = tid & 1;
        int rc = cbase + ((edge < ccnt) ? edge : (ccnt - 1));
        int gid = idxbuf[rc];
        int et = gid >> 15, le = gid & (NE1 - 1);
        int sn = (et ? src_intra : src_inter)[le];
        const uint4* rp = (const uint4*)(relh + (size_t)sn * RELHS);
        uint4* dp = (uint4*)&buf[edge * SSTR];
        int q0 = h * 13;
        int q1 = q0 + 13 - h;
        for (int q = q0; q < q1; ++q) dp[q] = rp[q];
    }
    __syncthreads();

    switch (kind) {
        case 0:  GATE_BODY(0, 7, 0, 2); break;
        case 1:  GATE_BODY(0, 7, 2, 4); break;
        case 2:  GATE_BODY(0, 7, 4, 6); break;
        case 3:  GATE_BODY(0, 7, 6, 7); break;
        case 4:  GATE_BODY(0, 4, 0, 2); break;
        case 5:  GATE_BODY(0, 4, 2, 4); break;
        case 6:  GATE_BODY(0, 4, 4, 6); break;
        case 7:  GATE_BODY(0, 4, 6, 7); break;
        case 8:  GATE_BODY(3, 7, 0, 2); break;
        case 9:  GATE_BODY(3, 7, 2, 4); break;
        case 10: GATE_BODY(3, 7, 4, 6); break;
        case 11: GATE_BODY(3, 7, 6, 7); break;
        default: break;
    }
}

// ---------------------------------------------------------------------------
extern "C" void kernel_launch(void* const* d_in, const int* in_sizes, int n_in,
                              void* d_out, int out_size, void* d_ws, size_t ws_size,
                              hipStream_t stream) {
    (void)in_sizes; (void)n_in; (void)out_size; (void)ws_size;
    const float* nmat     = (const float*)d_in[0];
    const float* e_inter  = (const float*)d_in[1];
    const float* e_intra  = (const float*)d_in[2];
    const float* W_bl     = (const float*)d_in[3];
    const float* W_bl1    = (const float*)d_in[4];
    const float* b_bl1    = (const float*)d_in[5];
    const int* src_inter  = (const int*)d_in[6];
    const int* dst_inter  = (const int*)d_in[7];
    const int* src_intra  = (const int*)d_in[8];
    const int* dst_intra  = (const int*)d_in[9];
    float* out = (float*)d_out;

    char* ws = (char*)d_ws;
    float* regA     = (float*)(ws + OFF_REL);
    half8* Bpk      = (half8*)(ws + OFF_BPK);
    int* idxbuf     = (int*)(ws + OFF_IDX);
    float* s_buf    = (float*)(ws + OFF_IDX);
    unsigned* smax  = (unsigned*)(ws + OFF_SMAX);
    float* denom    = (float*)(ws + OFF_DEN);
    unsigned* meta  = (unsigned*)(ws + OFF_META);
    uint4* desc     = (uint4*)(ws + OFF_DESC);
    half8* Wpk      = (half8*)(ws + OFF_WPK);

    hipMemsetAsync(smax, 0, 524288, stream);
    hipMemsetAsync(denom, 0, 524288, stream);
    hipMemsetAsync(meta, 0, 256, stream);

    build_bpk<<<(KI * KS * NT * 64 + 255) / 256, 256, 0, stream>>>(W_bl1, Bpk);
    build_wpk<<<(24 * NT * 64 + 255) / 256, 256, 0, stream>>>(W_bl, Wpk);
    proj_mfma<<<NN / 128, 512, 0, stream>>>(nmat, Wpk, regA);
    score_kernel<<<NEG / 4, 256, 0, stream>>>(regA, e_inter, e_intra, dst_inter, dst_intra,
                                              s_buf, smax);
    hipMemsetAsync(regA, 0, 52428800, stream);   // proj dead; regA becomes rel
    accum_kernel<<<NEG / 4, 256, 0, stream>>>(s_buf, e_inter, e_intra, dst_inter, dst_intra,
                                              smax, denom, regA);
    dinv_kernel<<<512, 256, 0, stream>>>(denom);
    pack_kernel<<<NN / 256, 256, 0, stream>>>(regA, denom);
    classify_kernel<<<NEG / 256, 256, 0, stream>>>(denom, src_inter, dst_inter,
                                                   src_intra, dst_intra, meta);
    setup1_kernel<<<1, 64, 0, stream>>>(meta);
    setup2_kernel<<<(NDESC_G + 255) / 256, 256, 0, stream>>>(meta, desc);
    scatter_kernel<<<NEG / 256, 256, 0, stream>>>(denom, src_inter, dst_inter,
                                                  src_intra, dst_intra, meta, idxbuf);
    skip_kernel<<<2048, 128, 0, stream>>>(meta, idxbuf, e_inter, e_intra, b_bl1, out);
    gate_all<<<NDESC_G, 128, 0, stream>>>((const _Float16*)regA, denom, Bpk, b_bl1,
                                          src_inter, dst_inter, src_intra, dst_intra,
                                          e_inter, e_intra, idxbuf, meta, desc, out);
}

// Round 19
// 537.933 us; speedup vs baseline: 1.4894x; 1.0526x over previous
//
#include <hip/hip_runtime.h>
#include <hip/hip_bf16.h>
#include <stdint.h>

// ---------------------------------------------------------------------------
// r16 proven configuration (measured 539 us total, gate 390 us):
//  K8 gate_all : EPB=64, 2 waves/blk, M=32/wave, NTT=2 pieces, time-shared
//                25.6 KB LDS, raw fp16 row-copy staging (1 thread/row,
//                unrolled), compile-time ks/t ranges via macro dispatch.
//
// ws layout (bytes): 63.7 MB total.
// ---------------------------------------------------------------------------

typedef __attribute__((ext_vector_type(8))) short short8;
typedef __attribute__((ext_vector_type(4))) float f32x4;
typedef _Float16 half8 __attribute__((ext_vector_type(8)));

#define NN 65536
#define NE1 32768
#define NEG 65536
#define DC 768
#define DR 97
#define DR2 194
#define RELSTR 200
#define RELHS 400
#define KI 194
#define KS 7
#define NT 7
#define EPB 64         // edges per gate block (2 waves x M=32)
#define SSTR 200
#define PSTR 72
#define NDESC_G 4160

#define OFF_REL   0ull
#define OFF_BPK   52428800ull
#define OFF_IDX   62164992ull
#define OFF_SMAX  62427136ull
#define OFF_DEN   62951424ull
#define OFF_META  63475712ull
#define OFF_DESC  63475968ull
#define OFF_WPK   63542528ull

static __device__ __forceinline__ unsigned fkey(float f) {
    unsigned b = __float_as_uint(f);
    return (b & 0x80000000u) ? ~b : (b | 0x80000000u);
}
static __device__ __forceinline__ float funkey(unsigned k) {
    return __uint_as_float((k & 0x80000000u) ? (k & 0x7fffffffu) : ~k);
}
static __device__ __forceinline__ unsigned pk2(_Float16 a, _Float16 b) {
    union { _Float16 h[2]; unsigned u; } x;
    x.h[0] = a; x.h[1] = b;
    return x.u;
}
static __device__ __forceinline__ int nstate(bool zi, bool zx) {
    return zi ? (zx ? 3 : 2) : (zx ? 1 : 0);
}
static __device__ __forceinline__ int nsplit_of(int b) { (void)b; return 4; }
static __device__ __forceinline__ int kindbase_of(int b) { return (b % 3) * 4; }

// ---------------- K1: W_bl1 -> Bpk (b-frag-packed fp16) --------------------
__global__ void build_bpk(const float* __restrict__ W, half8* __restrict__ Bpk) {
    int id = blockIdx.x * blockDim.x + threadIdx.x;
    const int total = KI * KS * NT * 64;
    if (id >= total) return;
    int l = id & 63;
    int g = id >> 6;
    int t = g % NT;
    int ks = (g / NT) % KS;
    int i = g / (NT * KS);
    int kk = t * 16 + (l & 15);
    int jb = ks * 32 + (l >> 4) * 8;
    half8 pk;
#pragma unroll
    for (int m = 0; m < 8; ++m) {
        int j = jb + m;
        float f = (kk < DR && j < DR2) ? W[(size_t)kk * (DR2 * DR2) + i * DR2 + j] : 0.f;
        pk[m] = (_Float16)f;
    }
    Bpk[id] = pk;
}

// ---------------- K1b: W_bl -> Wpk ------------------------------------------
__global__ void build_wpk(const float* __restrict__ Wb, half8* __restrict__ Wpk) {
    int id = blockIdx.x * blockDim.x + threadIdx.x;
    const int total = 24 * NT * 64;
    if (id >= total) return;
    int l = id & 63;
    int g = id >> 6;
    int t = g % NT;
    int k2 = g / NT;
    int col = t * 16 + (l & 15);
    int j0 = k2 * 32 + (l >> 4) * 8;
    half8 pk;
#pragma unroll
    for (int m = 0; m < 8; ++m) {
        float f = (col < DR) ? Wb[(size_t)(j0 + m) * DR + col] : 0.f;
        pk[m] = (_Float16)f;
    }
    Wpk[id] = pk;
}

// ---------------- K2: proj = n @ W_bl via MFMA -------------------------------
__launch_bounds__(512, 8)
__global__ void proj_mfma(const float* __restrict__ nmat, const half8* __restrict__ Wpk,
                          float* __restrict__ proj) {
    __shared__ __align__(16) _Float16 a_lds[128][PSTR];
    int tid = threadIdx.x;
    int r0 = blockIdx.x << 7;
    int w = tid >> 6, lane = tid & 63;
    int er = (w << 4) + (lane & 15);
    int lk = lane >> 4;

    f32x4 acc[NT];
#pragma unroll
    for (int t = 0; t < NT; ++t) acc[t] = (f32x4){0.f, 0.f, 0.f, 0.f};

    int srow = tid >> 2;
    int sc0 = (tid & 3) << 4;
    const float* nrow = nmat + (size_t)(r0 + srow) * DC + sc0;

    for (int k0 = 0; k0 < DC; k0 += 64) {
        __syncthreads();
        {
            const f32x4* p = (const f32x4*)(nrow + k0);
            _Float16* dst = &a_lds[srow][sc0];
#pragma unroll
            for (int q = 0; q < 4; ++q) {
                f32x4 v = p[q];
                *(unsigned*)&dst[q * 4]     = pk2((_Float16)v[0], (_Float16)v[1]);
                *(unsigned*)&dst[q * 4 + 2] = pk2((_Float16)v[2], (_Float16)v[3]);
            }
        }
        __syncthreads();
#pragma unroll
        for (int kk = 0; kk < 2; ++kk) {
            half8 af = *(const half8*)&a_lds[er][kk * 32 + lk * 8];
            const half8* bp = Wpk + (size_t)((k0 >> 5) + kk) * (NT * 64) + lane;
#pragma unroll
            for (int t = 0; t < NT; ++t)
                acc[t] = __builtin_amdgcn_mfma_f32_16x16x32_f16(af, bp[t * 64], acc[t], 0, 0, 0);
        }
    }

#pragma unroll
    for (int t = 0; t < NT; ++t) {
        int col = t * 16 + (lane & 15);
        if (col < DR) {
#pragma unroll
            for (int r = 0; r < 4; ++r) {
                int row = r0 + (w << 4) + lk * 4 + r;
                proj[(size_t)row * DR + col] = acc[t][r];
            }
        }
    }
}

// ---------------- K3: per-edge score + segment max --------------------------
__global__ void score_kernel(const float* __restrict__ proj,
                             const float* __restrict__ e_inter, const float* __restrict__ e_intra,
                             const int* __restrict__ dst_inter, const int* __restrict__ dst_intra,
                             float* __restrict__ s_buf, unsigned* __restrict__ smax_key) {
    int wid = (blockIdx.x * blockDim.x + threadIdx.x) >> 6;
    int lane = threadIdx.x & 63;
    if (wid >= NEG) return;
    int et = wid >> 15, le = wid & (NE1 - 1);
    const float* e = (et ? e_intra : e_inter) + (size_t)le * DR;
    int dst = (et ? dst_intra : dst_inter)[le];
    const float* pr = proj + (size_t)dst * DR;
    float p = pr[lane] * e[lane];
    if (lane < DR - 64) p += pr[lane + 64] * e[lane + 64];
#pragma unroll
    for (int off = 32; off > 0; off >>= 1) p += __shfl_down(p, off);
    if (lane == 0) {
        s_buf[wid] = p;
        atomicMax(&smax_key[et * NN + dst], fkey(p));
    }
}

// ---------------- K4: exp + segment sums ------------------------------------
__global__ void accum_kernel(const float* __restrict__ s_buf,
                             const float* __restrict__ e_inter, const float* __restrict__ e_intra,
                             const int* __restrict__ dst_inter, const int* __restrict__ dst_intra,
                             const unsigned* __restrict__ smax_key,
                             float* __restrict__ denom, float* __restrict__ rel) {
    int wid = (blockIdx.x * blockDim.x + threadIdx.x) >> 6;
    int lane = threadIdx.x & 63;
    if (wid >= NEG) return;
    int et = wid >> 15, le = wid & (NE1 - 1);
    const float* e = (et ? e_intra : e_inter) + (size_t)le * DR;
    int dst = (et ? dst_intra : dst_inter)[le];
    float s = s_buf[wid];
    float mx = funkey(smax_key[et * NN + dst]);
    float ex = __expf(s - mx);
    if (lane == 0) atomicAdd(&denom[et * NN + dst], ex);
    float* rrow = rel + (size_t)dst * RELSTR + et * DR;
    atomicAdd(&rrow[lane], e[lane] * ex);
    if (lane < DR - 64) atomicAdd(&rrow[lane + 64], e[lane + 64] * ex);
}

// ---------------- K5: denom -> 1/denom (0 if empty) -------------------------
__global__ void dinv_kernel(float* __restrict__ denom) {
    int i = blockIdx.x * blockDim.x + threadIdx.x;
    if (i < 2 * NN) {
        float d = denom[i];
        denom[i] = (d > 0.f) ? (1.f / d) : 0.f;
    }
}

// ---------------- K5b: pack rel f32 -> fp16 x dinv, IN PLACE ----------------
__global__ void pack_kernel(float* __restrict__ relf, const float* __restrict__ dinv) {
    int n = blockIdx.x * blockDim.x + threadIdx.x;
    if (n >= NN) return;
    float di0 = dinv[n], di1 = dinv[NN + n];
    unsigned* row = (unsigned*)(relf + (size_t)n * RELSTR);
#pragma unroll 10
    for (int q = 0; q < 50; ++q) {
        uint4 v = *(const uint4*)(row + q * 4);
        int c = q * 4;
        _Float16 h0 = (_Float16)(__uint_as_float(v.x) * ((c + 0 < DR) ? di0 : di1));
        _Float16 h1 = (_Float16)(__uint_as_float(v.y) * ((c + 1 < DR) ? di0 : di1));
        _Float16 h2 = (_Float16)(__uint_as_float(v.z) * ((c + 2 < DR) ? di0 : di1));
        _Float16 h3 = (_Float16)(__uint_as_float(v.w) * ((c + 3 < DR) ? di0 : di1));
        uint2 o;
        o.x = pk2(h0, h1);
        o.y = pk2(h2, h3);
        *(uint2*)(row + q * 2) = o;
    }
}

// ---------------- K6a: classify (LDS histogram) -----------------------------
__global__ void classify_kernel(const float* __restrict__ dinv,
                                const int* __restrict__ src_inter, const int* __restrict__ dst_inter,
                                const int* __restrict__ src_intra, const int* __restrict__ dst_intra,
                                unsigned* __restrict__ meta) {
    __shared__ unsigned h[16];
    if (threadIdx.x < 16) h[threadIdx.x] = 0;
    __syncthreads();
    int gid = blockIdx.x * blockDim.x + threadIdx.x;
    if (gid < NEG) {
        int et = gid >> 15, le = gid & (NE1 - 1);
        int sn = (et ? src_intra : src_inter)[le];
        int dn = (et ? dst_intra : dst_inter)[le];
        int ss = nstate(dinv[sn] == 0.f, dinv[NN + sn] == 0.f);
        int ds = nstate(dinv[dn] == 0.f, dinv[NN + dn] == 0.f);
        int b = (ss == 3 || ds == 3) ? 9 : ss * 3 + ds;
        atomicAdd(&h[b], 1u);
    }
    __syncthreads();
    if (threadIdx.x < 10 && h[threadIdx.x])
        atomicAdd(&meta[threadIdx.x], h[threadIdx.x]);
}

// ---------------- K6b: setup1 -------------------------------------------------
__global__ void setup1_kernel(unsigned* __restrict__ meta) {
    if (threadIdx.x != 0 || blockIdx.x != 0) return;
    unsigned run = 0;
    for (int b = 0; b < 10; ++b) {
        meta[32 + b] = run;
        meta[16 + b] = run;
        run += meta[b];
    }
    unsigned c = 0;
    for (int b = 0; b < 9; ++b) {
        meta[52 + b] = c;
        c += ((meta[b] + EPB - 1) / EPB) * (unsigned)nsplit_of(b);
    }
    meta[48] = c;
}

// ---------------- K6c: setup2 -------------------------------------------------
__global__ void setup2_kernel(const unsigned* __restrict__ meta, uint4* __restrict__ desc) {
    int j = blockIdx.x * blockDim.x + threadIdx.x;
    if (j >= (int)meta[48]) return;
    int b = 8;
    for (int q = 1; q < 9; ++q)
        if (j < (int)meta[52 + q]) { b = q - 1; break; }
    int p = j - (int)meta[52 + b];
    int ns = nsplit_of(b);
    int ci = p / ns;
    int si = p - ci * ns;
    int cnt = (int)meta[b];
    int cbase = (int)meta[32 + b] + ci * EPB;
    int ccnt = cnt - ci * EPB;
    if (ccnt > EPB) ccnt = EPB;
    int kind = kindbase_of(b) + si;
    int sclass = b / 3;
    desc[j] = make_uint4((unsigned)kind, (unsigned)cbase, (unsigned)ccnt, (unsigned)sclass);
}

// ---------------- K6d: scatter ------------------------------------------------
__global__ void scatter_kernel(const float* __restrict__ dinv,
                               const int* __restrict__ src_inter, const int* __restrict__ dst_inter,
                               const int* __restrict__ src_intra, const int* __restrict__ dst_intra,
                               unsigned* __restrict__ meta, int* __restrict__ idxbuf) {
    __shared__ unsigned cur[16];
    __shared__ unsigned base[16];
    if (threadIdx.x < 16) cur[threadIdx.x] = 0;
    __syncthreads();
    int gid = blockIdx.x * blockDim.x + threadIdx.x;
    int b = -1;
    unsigned r = 0;
    if (gid < NEG) {
        int et = gid >> 15, le = gid & (NE1 - 1);
        int sn = (et ? src_intra : src_inter)[le];
        int dn = (et ? dst_intra : dst_inter)[le];
        int ss = nstate(dinv[sn] == 0.f, dinv[NN + sn] == 0.f);
        int ds = nstate(dinv[dn] == 0.f, dinv[NN + dn] == 0.f);
        b = (ss == 3 || ds == 3) ? 9 : ss * 3 + ds;
        r = atomicAdd(&cur[b], 1u);
    }
    __syncthreads();
    if (threadIdx.x < 10 && cur[threadIdx.x])
        base[threadIdx.x] = atomicAdd(&meta[16 + threadIdx.x], cur[threadIdx.x]);
    __syncthreads();
    if (b >= 0) idxbuf[base[b] + r] = gid;
}

// ---------------- K7: skip-class edges --------------------------------------
__global__ void skip_kernel(const unsigned* __restrict__ meta, const int* __restrict__ idxbuf,
                            const float* __restrict__ e_inter, const float* __restrict__ e_intra,
                            const float* __restrict__ bias, float* __restrict__ out) {
    int n9 = (int)meta[9];
    int base9 = (int)meta[41];
    int k = threadIdx.x;
    float g = 0.f;
    if (k < DR) {
        float b = bias[k];
        g = 1.f + 1.f / (1.f + __expf(-b));
    }
    for (int q = blockIdx.x; q < n9; q += gridDim.x) {
        int gid = idxbuf[base9 + q];
        int et = gid >> 15, le = gid & (NE1 - 1);
        const float* e = (et ? e_intra : e_inter) + (size_t)le * DR;
        if (k < DR) out[(size_t)gid * DR + k] = e[k] * g;
    }
}

// ---------------- K8 compute body as MACRO (M=32/wave) ----------------------
#define GATE_BODY(KS0v, KS1v, T0v, T1v)                                        \
    {                                                                          \
        constexpr int NKSv = (KS1v) - (KS0v);                                  \
        constexpr int NTTv = (T1v) - (T0v);                                    \
        f32x4 acc0[NTTv], acc1[NTTv];                                          \
        _Pragma("unroll")                                                      \
        for (int tt = 0; tt < NTTv; ++tt) {                                    \
            acc0[tt] = (f32x4){0.f, 0.f, 0.f, 0.f};                            \
            acc1[tt] = (f32x4){0.f, 0.f, 0.f, 0.f};                            \
        }                                                                      \
        const half8* bl = Bpk + lane;                                          \
        for (int i = i0; i < iEnd; ++i) {                                      \
            _Float16 s0 = buf[er0 * SSTR + i];                                 \
            _Float16 s1 = buf[er1 * SSTR + i];                                 \
            half8 sv0 = {s0, s0, s0, s0, s0, s0, s0, s0};                      \
            half8 sv1 = {s1, s1, s1, s1, s1, s1, s1, s1};                      \
            const half8* bi = bl + (size_t)((i * KS + (KS0v)) * NT + (T0v)) * 64; \
            _Pragma("unroll")                                                  \
            for (int ks = 0; ks < NKSv; ++ks) {                                \
                half8 af0 = sv0 * dv0[(KS0v) + ks];                            \
                half8 af1 = sv1 * dv1[(KS0v) + ks];                            \
                _Pragma("unroll")                                              \
                for (int tt = 0; tt < NTTv; ++tt) {                            \
                    half8 bv = bi[(ks * NT + tt) * 64];                        \
                    acc0[tt] = __builtin_amdgcn_mfma_f32_16x16x32_f16(af0, bv, acc0[tt], 0, 0, 0); \
                    acc1[tt] = __builtin_amdgcn_mfma_f32_16x16x32_f16(af1, bv, acc1[tt], 0, 0, 0); \
                }                                                              \
            }                                                                  \
        }                                                                      \
        _Pragma("unroll")                                                      \
        for (int r = 0; r < 4; ++r) {                                          \
            int row = (w << 5) + lk * 4 + r;                                   \
            if (row < ccnt) {                                                  \
                int gid = idxbuf[cbase + row];                                 \
                int et = gid >> 15, le = gid & (NE1 - 1);                      \
                const float* e = (et ? e_intra : e_inter) + (size_t)le * DR;   \
                float* o = out + (size_t)gid * DR;                             \
                _Pragma("unroll")                                              \
                for (int tt = 0; tt < NTTv; ++tt) {                            \
                    int k = ((T0v) + tt) * 16 + (lane & 15);                   \
                    if (k < DR) {                                              \
                        float g = acc0[tt][r] + bias[k];                       \
                        float sg = 1.f / (1.f + __expf(-g));                   \
                        o[k] = e[k] * (1.f + sg);                              \
                    }                                                          \
                }                                                              \
            }                                                                  \
        }                                                                      \
        _Pragma("unroll")                                                      \
        for (int r = 0; r < 4; ++r) {                                          \
            int row = (w << 5) + 16 + lk * 4 + r;                              \
            if (row < ccnt) {                                                  \
                int gid = idxbuf[cbase + row];                                 \
                int et = gid >> 15, le = gid & (NE1 - 1);                      \
                const float* e = (et ? e_intra : e_inter) + (size_t)le * DR;   \
                float* o = out + (size_t)gid * DR;                             \
                _Pragma("unroll")                                              \
                for (int tt = 0; tt < NTTv; ++tt) {                            \
                    int k = ((T0v) + tt) * 16 + (lane & 15);                   \
                    if (k < DR) {                                              \
                        float g = acc1[tt][r] + bias[k];                       \
                        float sg = 1.f / (1.f + __expf(-g));                   \
                        o[k] = e[k] * (1.f + sg);                              \
                    }                                                          \
                }                                                              \
            }                                                                  \
        }                                                                      \
    }

// ---------------- K8: unified bilinear gate (EPB=64, 2 waves, M=32) ---------
__launch_bounds__(128, 4)
__global__ void gate_all(const _Float16* __restrict__ relh, const float* __restrict__ dinv,
                         const half8* __restrict__ Bpk, const float* __restrict__ bias,
                         const int* __restrict__ src_inter, const int* __restrict__ dst_inter,
                         const int* __restrict__ src_intra, const int* __restrict__ dst_intra,
                         const float* __restrict__ e_inter, const float* __restrict__ e_intra,
                         const int* __restrict__ idxbuf, const unsigned* __restrict__ meta,
                         const uint4* __restrict__ desc, float* __restrict__ out) {
    if (blockIdx.x >= meta[48]) return;
    uint4 de = desc[blockIdx.x];
    int kind = (int)de.x;
    int cbase = (int)de.y;
    int ccnt = (int)de.z;
    int sclass = (int)de.w;
    int i0 = (sclass == 2) ? DR : 0;
    int iEnd = (sclass == 0) ? DR2 : (i0 + DR);

    __shared__ __align__(16) _Float16 buf[EPB * SSTR];   // 25,600 B time-shared
    int tid = threadIdx.x;                                // 128
    int w = tid >> 6;                                     // wave 0..1
    int lane = tid & 63;
    int lk = lane >> 4;
    int er0 = (w << 5) + (lane & 15);
    int er1 = er0 + 16;

    // ---- phase 1: copy d rows (pre-scaled fp16) -> LDS ----
    if (tid < EPB) {
        int edge = tid;
        int rc = cbase + ((edge < ccnt) ? edge : (ccnt - 1));
        int gid = idxbuf[rc];
        int et = gid >> 15, le = gid & (NE1 - 1);
        int dn = (et ? dst_intra : dst_inter)[le];
        const uint4* rp = (const uint4*)(relh + (size_t)dn * RELHS);
        uint4* dp = (uint4*)&buf[edge * SSTR];
#pragma unroll
        for (int q = 0; q < 25; ++q) dp[q] = rp[q];
    }
    __syncthreads();

    half8 dv0[KS], dv1[KS];
#pragma unroll
    for (int ks = 0; ks < KS; ++ks) {
        if (ks == 6 && lk > 0) {
            dv0[ks] = (half8){0, 0, 0, 0, 0, 0, 0, 0};
            dv1[ks] = (half8){0, 0, 0, 0, 0, 0, 0, 0};
        } else {
            dv0[ks] = *(const half8*)&buf[er0 * SSTR + ks * 32 + lk * 8];
            dv1[ks] = *(const half8*)&buf[er1 * SSTR + ks * 32 + lk * 8];
        }
    }
    __syncthreads();

    // ---- phase 2: copy s rows into the SAME buffer ----
    if (tid < EPB) {
        int edge = tid;
        int rc = cbase + ((edge < ccnt) ? edge : (ccnt - 1));
        int gid = idxbuf[rc];
        int et = gid >> 15, le = gid & (NE1 - 1);
        int sn = (et ? src_intra : src_inter)[le];
        const uint4* rp = (const uint4*)(relh + (size_t)sn * RELHS);
        uint4* dp = (uint4*)&buf[edge * SSTR];
#pragma unroll
        for (int q = 0; q < 25; ++q) dp[q] = rp[q];
    }
    __syncthreads();

    switch (kind) {
        case 0:  GATE_BODY(0, 7, 0, 2); break;
        case 1:  GATE_BODY(0, 7, 2, 4); break;
        case 2:  GATE_BODY(0, 7, 4, 6); break;
        case 3:  GATE_BODY(0, 7, 6, 7); break;
        case 4:  GATE_BODY(0, 4, 0, 2); break;
        case 5:  GATE_BODY(0, 4, 2, 4); break;
        case 6:  GATE_BODY(0, 4, 4, 6); break;
        case 7:  GATE_BODY(0, 4, 6, 7); break;
        case 8:  GATE_BODY(3, 7, 0, 2); break;
        case 9:  GATE_BODY(3, 7, 2, 4); break;
        case 10: GATE_BODY(3, 7, 4, 6); break;
        case 11: GATE_BODY(3, 7, 6, 7); break;
        default: break;
    }
}

// ---------------------------------------------------------------------------
extern "C" void kernel_launch(void* const* d_in, const int* in_sizes, int n_in,
                              void* d_out, int out_size, void* d_ws, size_t ws_size,
                              hipStream_t stream) {
    (void)in_sizes; (void)n_in; (void)out_size; (void)ws_size;
    const float* nmat     = (const float*)d_in[0];
    const float* e_inter  = (const float*)d_in[1];
    const float* e_intra  = (const float*)d_in[2];
    const float* W_bl     = (const float*)d_in[3];
    const float* W_bl1    = (const float*)d_in[4];
    const float* b_bl1    = (const float*)d_in[5];
    const int* src_inter  = (const int*)d_in[6];
    const int* dst_inter  = (const int*)d_in[7];
    const int* src_intra  = (const int*)d_in[8];
    const int* dst_intra  = (const int*)d_in[9];
    float* out = (float*)d_out;

    char* ws = (char*)d_ws;
    float* regA     = (float*)(ws + OFF_REL);
    half8* Bpk      = (half8*)(ws + OFF_BPK);
    int* idxbuf     = (int*)(ws + OFF_IDX);
    float* s_buf    = (float*)(ws + OFF_IDX);
    unsigned* smax  = (unsigned*)(ws + OFF_SMAX);
    float* denom    = (float*)(ws + OFF_DEN);
    unsigned* meta  = (unsigned*)(ws + OFF_META);
    uint4* desc     = (uint4*)(ws + OFF_DESC);
    half8* Wpk      = (half8*)(ws + OFF_WPK);

    hipMemsetAsync(smax, 0, 524288, stream);
    hipMemsetAsync(denom, 0, 524288, stream);
    hipMemsetAsync(meta, 0, 256, stream);

    build_bpk<<<(KI * KS * NT * 64 + 255) / 256, 256, 0, stream>>>(W_bl1, Bpk);
    build_wpk<<<(24 * NT * 64 + 255) / 256, 256, 0, stream>>>(W_bl, Wpk);
    proj_mfma<<<NN / 128, 512, 0, stream>>>(nmat, Wpk, regA);
    score_kernel<<<NEG / 4, 256, 0, stream>>>(regA, e_inter, e_intra, dst_inter, dst_intra,
                                              s_buf, smax);
    hipMemsetAsync(regA, 0, 52428800, stream);   // proj dead; regA becomes rel
    accum_kernel<<<NEG / 4, 256, 0, stream>>>(s_buf, e_inter, e_intra, dst_inter, dst_intra,
                                              smax, denom, regA);
    dinv_kernel<<<512, 256, 0, stream>>>(denom);
    pack_kernel<<<NN / 256, 256, 0, stream>>>(regA, denom);
    classify_kernel<<<NEG / 256, 256, 0, stream>>>(denom, src_inter, dst_inter,
                                                   src_intra, dst_intra, meta);
    setup1_kernel<<<1, 64, 0, stream>>>(meta);
    setup2_kernel<<<(NDESC_G + 255) / 256, 256, 0, stream>>>(meta, desc);
    scatter_kernel<<<NEG / 256, 256, 0, stream>>>(denom, src_inter, dst_inter,
                                                  src_intra, dst_intra, meta, idxbuf);
    skip_kernel<<<2048, 128, 0, stream>>>(meta, idxbuf, e_inter, e_intra, b_bl1, out);
    gate_all<<<NDESC_G, 128, 0, stream>>>((const _Float16*)regA, denom, Bpk, b_bl1,
                                          src_inter, dst_inter, src_intra, dst_intra,
                                          e_inter, e_intra, idxbuf, meta, desc, out);
}